// Round 6
// baseline (43.155 us; speedup 1.0000x reference)
//
#include <hip/hip_runtime.h>
#include <math.h>

constexpr int NB    = 128;
constexpr int NPAIR = NB * (NB - 1) / 2;        // 8128
constexpr int NANG  = NB - 2;                   // 126
constexpr int NDIH  = NB - 3;                   // 125
constexpr int ROW   = NPAIR + NANG + 2 * NDIH;  // 8504
constexpr int PP    = 4;                         // proteins per block (lockstep window)

__global__ __launch_bounds__(128, 8) void protein_feat_kernel(
        const float* __restrict__ data, float* __restrict__ out, int batch) {
    __shared__ float4 s4[NB];                    // (x,y,z,0) per bead
    const int t = threadIdx.x;                   // 0..127 == bead index

    for (int k = 0; k < PP; ++k) {
        const int p = blockIdx.x + gridDim.x * k;   // all blocks at same window
        if (p >= batch) break;

        __syncthreads();                            // previous protein's s4 done
        const float* src = data + (size_t)p * (NB * 3);
        s4[t] = make_float4(src[3 * t], src[3 * t + 1], src[3 * t + 2], 0.0f);
        __syncthreads();

        float* orow = out + (size_t)p * ROW;

        // Register band: lane t holds beads t, t-1, t-2, t-3.
        float px[4], py[4], pz[4];
        #pragma unroll
        for (int q = 0; q < 4; ++q) {
            int idx = t - q; if (idx < 0) idx = 0;  // clamped; masked at store
            float4 v = s4[idx];
            px[q] = v.x; py[q] = v.y; pz[q] = v.z;
        }

        // ---- Distances: 4 rows per ds_read_b128 (conflict-free, coalesced).
        int base = 0;                               // row-base B(off), B(1)=0
        #pragma unroll 2
        for (int off = 1; off < NB; off += 4) {
            const int len = NB - off;
            int bk0 = base;
            int bk1 = bk0 + len;
            int bk2 = bk1 + len - 1;
            int bk3 = bk2 + len - 2;
            base    = bk3 + len - 3;                // B(off+4)
            if (t < len) {                          // wave 1 execz-skips off>63
                float4 pj = s4[t + off];
                float dx, dy, dz, d;
                dx = pj.x - px[0]; dy = pj.y - py[0]; dz = pj.z - pz[0];
                d = __builtin_amdgcn_sqrtf(dx*dx + dy*dy + dz*dz);
                orow[bk0 + t] = d;
                dx = pj.x - px[1]; dy = pj.y - py[1]; dz = pj.z - pz[1];
                d = __builtin_amdgcn_sqrtf(dx*dx + dy*dy + dz*dz);
                if (t >= 1) orow[bk1 + t - 1] = d;
                dx = pj.x - px[2]; dy = pj.y - py[2]; dz = pj.z - pz[2];
                d = __builtin_amdgcn_sqrtf(dx*dx + dy*dy + dz*dz);
                if (t >= 2) orow[bk2 + t - 2] = d;
                dx = pj.x - px[3]; dy = pj.y - py[3]; dz = pj.z - pz[3];
                d = __builtin_amdgcn_sqrtf(dx*dx + dy*dy + dz*dz);
                if (t >= 3) orow[bk3 + t - 3] = d;
            }
        }

        // ---- Angles (126) + dihedral cos (125) + dihedral sin (125).
        for (int v = t; v < NANG + 2 * NDIH; v += 128) {
            if (v < NANG) {
                int a = v;
                float4 p0 = s4[a], p1 = s4[a + 1], p2 = s4[a + 2];
                float a0x = p1.x - p0.x, a0y = p1.y - p0.y, a0z = p1.z - p0.z;
                float a1x = p2.x - p1.x, a1y = p2.y - p1.y, a1z = p2.z - p1.z;
                float d  = a0x * a1x + a0y * a1y + a0z * a1z;
                float r0 = rsqrtf(a0x * a0x + a0y * a0y + a0z * a0z);
                float r1 = rsqrtf(a1x * a1x + a1y * a1y + a1z * a1z);
                float c  = d * r0 * r1;
                c = fminf(1.0f, fmaxf(-1.0f, c));
                orow[NPAIR + a] = acosf(c);
            } else {
                int a = (v < NANG + NDIH) ? (v - NANG) : (v - NANG - NDIH);
                float4 p0 = s4[a], p1 = s4[a + 1], p2 = s4[a + 2], p3 = s4[a + 3];
                float e0x = p1.x - p0.x, e0y = p1.y - p0.y, e0z = p1.z - p0.z;
                float e1x = p2.x - p1.x, e1y = p2.y - p1.y, e1z = p2.z - p1.z;
                float e2x = p3.x - p2.x, e2y = p3.y - p2.y, e2z = p3.z - p2.z;
                float c0x = e0y * e1z - e0z * e1y;
                float c0y = e0z * e1x - e0x * e1z;
                float c0z = e0x * e1y - e0y * e1x;
                float c1x = e1y * e2z - e1z * e2y;
                float c1y = e1z * e2x - e1x * e2z;
                float c1z = e1x * e2y - e1y * e2x;
                float rn0 = rsqrtf(c0x * c0x + c0y * c0y + c0z * c0z);
                if (v < NANG + NDIH) {
                    float d   = c0x * c1x + c0y * c1y + c0z * c1z;
                    float rn1 = rsqrtf(c1x * c1x + c1y * c1y + c1z * c1z);
                    orow[NPAIR + NANG + a] = d * rn0 * rn1;
                } else {
                    float qx = c1y * e1z - c1z * e1y;   // plane = c1 x e1
                    float qy = c1z * e1x - c1x * e1z;
                    float qz = c1x * e1y - c1y * e1x;
                    float d  = c0x * qx + c0y * qy + c0z * qz;
                    float rp = rsqrtf(qx * qx + qy * qy + qz * qz);
                    orow[NPAIR + NANG + NDIH + a] = d * rn0 * rp;
                }
            }
        }
    }
}

extern "C" void kernel_launch(void* const* d_in, const int* in_sizes, int n_in,
                              void* d_out, int out_size, void* d_ws, size_t ws_size,
                              hipStream_t stream) {
    const float* data = (const float*)d_in[0];
    float* out = (float*)d_out;
    const int batch = in_sizes[0] / (NB * 3);        // 4096
    const int grid  = (batch + PP - 1) / PP;         // 1024
    protein_feat_kernel<<<grid, 128, 0, stream>>>(data, out, batch);
}

// Round 7
// 35.058 us; speedup vs baseline: 1.2310x; 1.2310x over previous
//
#include <hip/hip_runtime.h>
#include <math.h>

constexpr int NB    = 128;
constexpr int NPAIR = NB * (NB - 1) / 2;        // 8128
constexpr int NANG  = NB - 2;                   // 126
constexpr int NDIH  = NB - 3;                   // 125
constexpr int ROW   = NPAIR + NANG + 2 * NDIH;  // 8504 (x4B = 34016, 16B-aligned)

__global__ __launch_bounds__(256, 4) void protein_feat_kernel(
        const float* __restrict__ data, float* __restrict__ out) {
    __shared__ float4 s4[NB];        // (x,y,z,0) per bead       (2 KB)
    __shared__ float  sfeat[ROW];    // LDS image of output row (34 KB)
    const int b  = blockIdx.x;
    const int t  = threadIdx.x;      // 0..255
    const int tb = t & 127;          // bead index
    const int g  = t >> 7;           // row group 0/1 (uniform per wave)
    const float* src = data + (size_t)b * (NB * 3);

    if (t < NB)
        s4[t] = make_float4(src[3 * t], src[3 * t + 1], src[3 * t + 2], 0.0f);
    __syncthreads();

    // Register band: lane holds beads tb, tb-1, tb-2, tb-3.
    float px[4], py[4], pz[4];
    #pragma unroll
    for (int k = 0; k < 4; ++k) {
        int idx = tb - k; if (idx < 0) idx = 0;   // clamped; masked at store
        float4 v = s4[idx];
        px[k] = v.x; py[k] = v.y; pz[k] = v.z;
    }

    // ---- Distances into sfeat: group g handles off = 1+4g+8m, 4 rows per
    // ds_read_b128 (conflict-free); LDS writes stride-1 (conflict-free).
    #pragma unroll 2
    for (int m = 0; m < 16; ++m) {
        const int off = 1 + 4 * g + 8 * m;
        const int len = NB - off;
        const int bk0 = (off - 1) * (2 * NB - off) / 2;  // B(off)=(off-1)(256-off)/2
        const int bk1 = bk0 + len;
        const int bk2 = bk1 + len - 1;
        const int bk3 = bk2 + len - 2;
        if (tb < len) {                          // also bounds s4[tb+off]
            float4 pj = s4[tb + off];
            float dx, dy, dz, d;
            dx = pj.x - px[0]; dy = pj.y - py[0]; dz = pj.z - pz[0];
            d = __builtin_amdgcn_sqrtf(dx*dx + dy*dy + dz*dz);
            sfeat[bk0 + tb] = d;
            dx = pj.x - px[1]; dy = pj.y - py[1]; dz = pj.z - pz[1];
            d = __builtin_amdgcn_sqrtf(dx*dx + dy*dy + dz*dz);
            if (tb >= 1) sfeat[bk1 + tb - 1] = d;
            dx = pj.x - px[2]; dy = pj.y - py[2]; dz = pj.z - pz[2];
            d = __builtin_amdgcn_sqrtf(dx*dx + dy*dy + dz*dz);
            if (tb >= 2) sfeat[bk2 + tb - 2] = d;
            dx = pj.x - px[3]; dy = pj.y - py[3]; dz = pj.z - pz[3];
            d = __builtin_amdgcn_sqrtf(dx*dx + dy*dy + dz*dz);
            if (tb >= 3) sfeat[bk3 + tb - 3] = d;
        }
    }

    // ---- Angles (126) + dihedral cos (125) + dihedral sin (125) into sfeat.
    for (int v = t; v < NANG + 2 * NDIH; v += 256) {
        if (v < NANG) {
            int a = v;
            float4 p0 = s4[a], p1 = s4[a + 1], p2 = s4[a + 2];
            float a0x = p1.x - p0.x, a0y = p1.y - p0.y, a0z = p1.z - p0.z;
            float a1x = p2.x - p1.x, a1y = p2.y - p1.y, a1z = p2.z - p1.z;
            float d  = a0x * a1x + a0y * a1y + a0z * a1z;
            float r0 = rsqrtf(a0x * a0x + a0y * a0y + a0z * a0z);
            float r1 = rsqrtf(a1x * a1x + a1y * a1y + a1z * a1z);
            float c  = d * r0 * r1;
            c = fminf(1.0f, fmaxf(-1.0f, c));
            sfeat[NPAIR + a] = acosf(c);
        } else {
            int a = (v < NANG + NDIH) ? (v - NANG) : (v - NANG - NDIH);
            float4 p0 = s4[a], p1 = s4[a + 1], p2 = s4[a + 2], p3 = s4[a + 3];
            float e0x = p1.x - p0.x, e0y = p1.y - p0.y, e0z = p1.z - p0.z;
            float e1x = p2.x - p1.x, e1y = p2.y - p1.y, e1z = p2.z - p1.z;
            float e2x = p3.x - p2.x, e2y = p3.y - p2.y, e2z = p3.z - p2.z;
            float c0x = e0y * e1z - e0z * e1y;
            float c0y = e0z * e1x - e0x * e1z;
            float c0z = e0x * e1y - e0y * e1x;
            float c1x = e1y * e2z - e1z * e2y;
            float c1y = e1z * e2x - e1x * e2z;
            float c1z = e1x * e2y - e1y * e2x;
            float rn0 = rsqrtf(c0x * c0x + c0y * c0y + c0z * c0z);
            if (v < NANG + NDIH) {
                float d   = c0x * c1x + c0y * c1y + c0z * c1z;
                float rn1 = rsqrtf(c1x * c1x + c1y * c1y + c1z * c1z);
                sfeat[NPAIR + NANG + a] = d * rn0 * rn1;
            } else {
                float qx = c1y * e1z - c1z * e1y;   // plane = c1 x e1
                float qy = c1z * e1x - c1x * e1z;
                float qz = c1x * e1y - c1y * e1x;
                float d  = c0x * qx + c0y * qy + c0z * qz;
                float rp = rsqrtf(qx * qx + qy * qy + qz * qz);
                sfeat[NPAIR + NANG + NDIH + a] = d * rn0 * rp;
            }
        }
    }

    __syncthreads();

    // ---- Flush: contiguous, 16B-aligned dwordx4 stream (fill-kernel pattern).
    float4*       dst = reinterpret_cast<float4*>(out + (size_t)b * ROW);
    const float4* sf4 = reinterpret_cast<const float4*>(sfeat);
    #pragma unroll 2
    for (int q = t; q < ROW / 4; q += 256)      // 2126 float4
        dst[q] = sf4[q];
}

extern "C" void kernel_launch(void* const* d_in, const int* in_sizes, int n_in,
                              void* d_out, int out_size, void* d_ws, size_t ws_size,
                              hipStream_t stream) {
    const float* data = (const float*)d_in[0];
    float* out = (float*)d_out;
    const int batch = in_sizes[0] / (NB * 3);   // 4096
    protein_feat_kernel<<<batch, 256, 0, stream>>>(data, out);
}

// Round 8
// 33.627 us; speedup vs baseline: 1.2833x; 1.0425x over previous
//
#include <hip/hip_runtime.h>
#include <math.h>

constexpr int NB    = 128;
constexpr int NPAIR = NB * (NB - 1) / 2;        // 8128
constexpr int NANG  = NB - 2;                   // 126
constexpr int NDIH  = NB - 3;                   // 125
constexpr int ROW   = NPAIR + NANG + 2 * NDIH;  // 8504
constexpr int NXCD  = 8;

__global__ __launch_bounds__(128, 8) void protein_feat_kernel(
        const float* __restrict__ data, float* __restrict__ out, int batch) {
    __shared__ float4 s4[NB];                    // (x,y,z,0) per bead
    const int t = threadIdx.x;                   // 0..127 == bead index

    // XCD-aware bijective remap (m204): blocks resident on one XCD cover a
    // CONTIGUOUS protein window -> per-XCD L2 write-back drains in address
    // order instead of random 34KB-region interleave.
    const int chunk = gridDim.x / NXCD;          // 4096/8 = 512, exact
    const int b = (blockIdx.x % NXCD) * chunk + blockIdx.x / NXCD;

    const float* src = data + (size_t)b * (NB * 3);
    s4[t] = make_float4(src[3 * t], src[3 * t + 1], src[3 * t + 2], 0.0f);
    __syncthreads();

    float* orow = out + (size_t)b * ROW;

    // Register band: lane t holds beads t, t-1, t-2, t-3.
    float px[4], py[4], pz[4];
    #pragma unroll
    for (int k = 0; k < 4; ++k) {
        int idx = t - k; if (idx < 0) idx = 0;   // clamped; masked at store
        float4 v = s4[idx];
        px[k] = v.x; py[k] = v.y; pz[k] = v.z;
    }

    // ---- Distances: 4 rows per ds_read_b128 (conflict-free, coalesced).
    int base = 0;                                // row-base B(off), B(1)=0
    #pragma unroll 2
    for (int off = 1; off < NB; off += 4) {
        const int len = NB - off;
        int bk0 = base;
        int bk1 = bk0 + len;
        int bk2 = bk1 + len - 1;
        int bk3 = bk2 + len - 2;
        base    = bk3 + len - 3;                 // B(off+4)
        if (t < len) {                           // wave 1 execz-skips off>63
            float4 pj = s4[t + off];
            float dx, dy, dz, d;
            dx = pj.x - px[0]; dy = pj.y - py[0]; dz = pj.z - pz[0];
            d = __builtin_amdgcn_sqrtf(dx*dx + dy*dy + dz*dz);
            orow[bk0 + t] = d;
            dx = pj.x - px[1]; dy = pj.y - py[1]; dz = pj.z - pz[1];
            d = __builtin_amdgcn_sqrtf(dx*dx + dy*dy + dz*dz);
            if (t >= 1) orow[bk1 + t - 1] = d;
            dx = pj.x - px[2]; dy = pj.y - py[2]; dz = pj.z - pz[2];
            d = __builtin_amdgcn_sqrtf(dx*dx + dy*dy + dz*dz);
            if (t >= 2) orow[bk2 + t - 2] = d;
            dx = pj.x - px[3]; dy = pj.y - py[3]; dz = pj.z - pz[3];
            d = __builtin_amdgcn_sqrtf(dx*dx + dy*dy + dz*dz);
            if (t >= 3) orow[bk3 + t - 3] = d;
        }
    }

    // ---- Angles (126) + dihedral cos (125) + dihedral sin (125).
    for (int v = t; v < NANG + 2 * NDIH; v += 128) {
        if (v < NANG) {
            int a = v;
            float4 p0 = s4[a], p1 = s4[a + 1], p2 = s4[a + 2];
            float a0x = p1.x - p0.x, a0y = p1.y - p0.y, a0z = p1.z - p0.z;
            float a1x = p2.x - p1.x, a1y = p2.y - p1.y, a1z = p2.z - p1.z;
            float d  = a0x * a1x + a0y * a1y + a0z * a1z;
            float r0 = rsqrtf(a0x * a0x + a0y * a0y + a0z * a0z);
            float r1 = rsqrtf(a1x * a1x + a1y * a1y + a1z * a1z);
            float c  = d * r0 * r1;
            c = fminf(1.0f, fmaxf(-1.0f, c));
            orow[NPAIR + a] = acosf(c);
        } else {
            int a = (v < NANG + NDIH) ? (v - NANG) : (v - NANG - NDIH);
            float4 p0 = s4[a], p1 = s4[a + 1], p2 = s4[a + 2], p3 = s4[a + 3];
            float e0x = p1.x - p0.x, e0y = p1.y - p0.y, e0z = p1.z - p0.z;
            float e1x = p2.x - p1.x, e1y = p2.y - p1.y, e1z = p2.z - p1.z;
            float e2x = p3.x - p2.x, e2y = p3.y - p2.y, e2z = p3.z - p2.z;
            float c0x = e0y * e1z - e0z * e1y;
            float c0y = e0z * e1x - e0x * e1z;
            float c0z = e0x * e1y - e0y * e1x;
            float c1x = e1y * e2z - e1z * e2y;
            float c1y = e1z * e2x - e1x * e2z;
            float c1z = e1x * e2y - e1y * e2x;
            float rn0 = rsqrtf(c0x * c0x + c0y * c0y + c0z * c0z);
            if (v < NANG + NDIH) {
                float d   = c0x * c1x + c0y * c1y + c0z * c1z;
                float rn1 = rsqrtf(c1x * c1x + c1y * c1y + c1z * c1z);
                orow[NPAIR + NANG + a] = d * rn0 * rn1;
            } else {
                float qx = c1y * e1z - c1z * e1y;   // plane = c1 x e1
                float qy = c1z * e1x - c1x * e1z;
                float qz = c1x * e1y - c1y * e1x;
                float d  = c0x * qx + c0y * qy + c0z * qz;
                float rp = rsqrtf(qx * qx + qy * qy + qz * qz);
                orow[NPAIR + NANG + NDIH + a] = d * rn0 * rp;
            }
        }
    }
}

extern "C" void kernel_launch(void* const* d_in, const int* in_sizes, int n_in,
                              void* d_out, int out_size, void* d_ws, size_t ws_size,
                              hipStream_t stream) {
    const float* data = (const float*)d_in[0];
    float* out = (float*)d_out;
    const int batch = in_sizes[0] / (NB * 3);   // 4096
    protein_feat_kernel<<<batch, 128, 0, stream>>>(data, out, batch);
}

// Round 9
// 31.339 us; speedup vs baseline: 1.3770x; 1.0730x over previous
//
#include <hip/hip_runtime.h>
#include <math.h>

constexpr int NB    = 128;
constexpr int NPAIR = NB * (NB - 1) / 2;        // 8128
constexpr int NANG  = NB - 2;                   // 126
constexpr int NDIH  = NB - 3;                   // 125
constexpr int ROW   = NPAIR + NANG + 2 * NDIH;  // 8504

// One protein per 1024-thread block: 2 blocks/CU resident -> only 512
// concurrent 34KB write regions chip-wide (vs 4096 with 128-thr blocks),
// while keeping 32 waves/CU. Goal: HBM row-buffer locality for the stores.
__global__ __launch_bounds__(1024, 8) void protein_feat_kernel(
        const float* __restrict__ data, float* __restrict__ out) {
    __shared__ float4 s4[NB];                    // (x,y,z,0) per bead
    const int b  = blockIdx.x;
    const int t  = threadIdx.x;                  // 0..1023
    const int tb = t & 127;                      // bead index
    const int g  = t >> 7;                       // off-group 0..7 (wave-uniform)
    const float* src = data + (size_t)b * (NB * 3);

    if (t < NB)
        s4[t] = make_float4(src[3 * t], src[3 * t + 1], src[3 * t + 2], 0.0f);
    __syncthreads();

    float* orow = out + (size_t)b * ROW;

    // Register band: lane holds beads tb, tb-1, tb-2, tb-3.
    float px[4], py[4], pz[4];
    #pragma unroll
    for (int k = 0; k < 4; ++k) {
        int idx = tb - k; if (idx < 0) idx = 0;  // clamped; masked at store
        float4 v = s4[idx];
        px[k] = v.x; py[k] = v.y; pz[k] = v.z;
    }

    // ---- Distances: group g handles off = 1+4g+32m (m=0..3), 4 rows per
    // ds_read_b128 (conflict-free reads, stride-1 coalesced stores).
    #pragma unroll
    for (int m = 0; m < 4; ++m) {
        const int off = 1 + 4 * g + 32 * m;
        const int len = NB - off;
        const int bk0 = (off - 1) * (2 * NB - off) / 2;  // B(off)
        const int bk1 = bk0 + len;
        const int bk2 = bk1 + len - 1;
        const int bk3 = bk2 + len - 2;
        if (tb < len) {                          // upper wave execz-skips len<=64
            float4 pj = s4[tb + off];
            float dx, dy, dz, d;
            dx = pj.x - px[0]; dy = pj.y - py[0]; dz = pj.z - pz[0];
            d = __builtin_amdgcn_sqrtf(dx*dx + dy*dy + dz*dz);
            orow[bk0 + tb] = d;
            dx = pj.x - px[1]; dy = pj.y - py[1]; dz = pj.z - pz[1];
            d = __builtin_amdgcn_sqrtf(dx*dx + dy*dy + dz*dz);
            if (tb >= 1) orow[bk1 + tb - 1] = d;
            dx = pj.x - px[2]; dy = pj.y - py[2]; dz = pj.z - pz[2];
            d = __builtin_amdgcn_sqrtf(dx*dx + dy*dy + dz*dz);
            if (tb >= 2) orow[bk2 + tb - 2] = d;
            dx = pj.x - px[3]; dy = pj.y - py[3]; dz = pj.z - pz[3];
            d = __builtin_amdgcn_sqrtf(dx*dx + dy*dy + dz*dz);
            if (tb >= 3) orow[bk3 + tb - 3] = d;
        }
    }

    // ---- Angles (126) + dihedral cos (125) + dihedral sin (125): t<376 only.
    const int v = t;
    if (v < NANG + 2 * NDIH) {
        if (v < NANG) {
            int a = v;
            float4 p0 = s4[a], p1 = s4[a + 1], p2 = s4[a + 2];
            float a0x = p1.x - p0.x, a0y = p1.y - p0.y, a0z = p1.z - p0.z;
            float a1x = p2.x - p1.x, a1y = p2.y - p1.y, a1z = p2.z - p1.z;
            float d  = a0x * a1x + a0y * a1y + a0z * a1z;
            float r0 = rsqrtf(a0x * a0x + a0y * a0y + a0z * a0z);
            float r1 = rsqrtf(a1x * a1x + a1y * a1y + a1z * a1z);
            float c  = d * r0 * r1;
            c = fminf(1.0f, fmaxf(-1.0f, c));
            orow[NPAIR + a] = acosf(c);
        } else {
            int a = (v < NANG + NDIH) ? (v - NANG) : (v - NANG - NDIH);
            float4 p0 = s4[a], p1 = s4[a + 1], p2 = s4[a + 2], p3 = s4[a + 3];
            float e0x = p1.x - p0.x, e0y = p1.y - p0.y, e0z = p1.z - p0.z;
            float e1x = p2.x - p1.x, e1y = p2.y - p1.y, e1z = p2.z - p1.z;
            float e2x = p3.x - p2.x, e2y = p3.y - p2.y, e2z = p3.z - p2.z;
            float c0x = e0y * e1z - e0z * e1y;
            float c0y = e0z * e1x - e0x * e1z;
            float c0z = e0x * e1y - e0y * e1x;
            float c1x = e1y * e2z - e1z * e2y;
            float c1y = e1z * e2x - e1x * e2z;
            float c1z = e1x * e2y - e1y * e2x;
            float rn0 = rsqrtf(c0x * c0x + c0y * c0y + c0z * c0z);
            if (v < NANG + NDIH) {
                float d   = c0x * c1x + c0y * c1y + c0z * c1z;
                float rn1 = rsqrtf(c1x * c1x + c1y * c1y + c1z * c1z);
                orow[NPAIR + NANG + a] = d * rn0 * rn1;
            } else {
                float qx = c1y * e1z - c1z * e1y;   // plane = c1 x e1
                float qy = c1z * e1x - c1x * e1z;
                float qz = c1x * e1y - c1y * e1x;
                float d  = c0x * qx + c0y * qy + c0z * qz;
                float rp = rsqrtf(qx * qx + qy * qy + qz * qz);
                orow[NPAIR + NANG + NDIH + a] = d * rn0 * rp;
            }
        }
    }
}

extern "C" void kernel_launch(void* const* d_in, const int* in_sizes, int n_in,
                              void* d_out, int out_size, void* d_ws, size_t ws_size,
                              hipStream_t stream) {
    const float* data = (const float*)d_in[0];
    float* out = (float*)d_out;
    const int batch = in_sizes[0] / (NB * 3);   // 4096
    protein_feat_kernel<<<batch, 1024, 0, stream>>>(data, out);
}